// Round 1
// baseline (169.770 us; speedup 1.0000x reference)
//
#include <hip/hip_runtime.h>
#include <math.h>

#define NQ  12
#define NST 4096   // 2^12 amplitudes

// ---------------------------------------------------------------------------
// Kernel A: full statevector simulation in LDS (32 KiB), one block / one CU.
// Flat index convention: qubit q is bit (11-q) of the flat index (C-order,
// axis 0 most significant) — matches jnp (2,)*12 tensor layout.
// ---------------------------------------------------------------------------
__global__ __launch_bounds__(1024) void circuit_kernel(
    const float* __restrict__ qw,   // (3,12,3)
    const float* __restrict__ W1,   // (32,12)
    const float* __restrict__ b1,   // (32,)
    const float* __restrict__ W2,   // (16,32)
    const float* __restrict__ b2,   // (16,)
    float* __restrict__ pix)        // 16 outputs -> d_ws
{
    __shared__ float sre[NST];
    __shared__ float smi[NST];
    __shared__ float sz[NQ];
    __shared__ float sh[32];

    const int tid = threadIdx.x;

    for (int i = tid; i < NST; i += 1024) { sre[i] = 0.f; smi[i] = 0.f; }
    if (tid == 0) sre[0] = 1.f;
    __syncthreads();

    for (int l = 0; l < 3; ++l) {
        // ---- single-qubit layer: U = RZ @ RY @ RX on each wire ----
        for (int q = 0; q < NQ; ++q) {
            const float tx = qw[(l*NQ + q)*3 + 0];
            const float ty = qw[(l*NQ + q)*3 + 1];
            const float tz = qw[(l*NQ + q)*3 + 2];
            const float cx = cosf(0.5f*tx), sx = sinf(0.5f*tx);
            const float cy = cosf(0.5f*ty), sy = sinf(0.5f*ty);
            const float cz = cosf(0.5f*tz), s_z = sinf(0.5f*tz);
            // A = RY @ RX
            const float a00r =  cy*cx, a00i =  sy*sx;
            const float a01r = -sy*cx, a01i = -cy*sx;
            const float a10r =  sy*cx, a10i = -cy*sx;
            const float a11r =  cy*cx, a11i = -sy*sx;
            // U row0 = e^{-i tz/2} * A row0 ; U row1 = e^{+i tz/2} * A row1
            const float u00r = cz*a00r + s_z*a00i, u00i = cz*a00i - s_z*a00r;
            const float u01r = cz*a01r + s_z*a01i, u01i = cz*a01i - s_z*a01r;
            const float u10r = cz*a10r - s_z*a10i, u10i = cz*a10i + s_z*a10r;
            const float u11r = cz*a11r - s_z*a11i, u11i = cz*a11i + s_z*a11r;

            const int bit = 1 << (11 - q);
            for (int p = tid; p < NST/2; p += 1024) {
                const int i0 = ((p & ~(bit-1)) << 1) | (p & (bit-1));
                const int i1 = i0 | bit;
                const float r0 = sre[i0], m0 = smi[i0];
                const float r1 = sre[i1], m1 = smi[i1];
                sre[i0] = u00r*r0 - u00i*m0 + u01r*r1 - u01i*m1;
                smi[i0] = u00r*m0 + u00i*r0 + u01r*m1 + u01i*r1;
                sre[i1] = u10r*r0 - u10i*m0 + u11r*r1 - u11i*m1;
                smi[i1] = u10r*m0 + u10i*r0 + u11r*m1 + u11i*r1;
            }
            __syncthreads();
        }
        // ---- CNOT ring: CNOT(q, (q+1)%12) ----
        for (int q = 0; q < NQ; ++q) {
            const int c = q, t = (q + 1) % NQ;
            const int cb = 1 << (11 - c), tb = 1 << (11 - t);
            const int lo = cb < tb ? cb : tb;
            const int hi = cb < tb ? tb : cb;
            // 1024 pairs: enumerate indices with cb and tb both clear, then
            // set control=1; swap target 0 <-> 1.
            for (int p = tid; p < NST/4; p += 1024) {
                int x = ((p & ~(lo-1)) << 1) | (p & (lo-1));
                x     = ((x & ~(hi-1)) << 1) | (x & (hi-1));
                const int i0 = x | cb;
                const int i1 = i0 | tb;
                float r = sre[i0]; sre[i0] = sre[i1]; sre[i1] = r;
                float m = smi[i0]; smi[i0] = smi[i1]; smi[i1] = m;
            }
            __syncthreads();
        }
    }

    // ---- <Z_q> per qubit: wave w (0..11) reduces qubit w ----
    const int lane = tid & 63;
    const int w    = tid >> 6;
    if (w < NQ) {
        const int bit = 1 << (11 - w);
        float s = 0.f;
        for (int i = lane; i < NST; i += 64) {
            const float p = sre[i]*sre[i] + smi[i]*smi[i];
            s += (i & bit) ? -p : p;
        }
        #pragma unroll
        for (int off = 32; off > 0; off >>= 1) s += __shfl_down(s, off, 64);
        if (lane == 0) sz[w] = s;
    }
    __syncthreads();

    // ---- MLP: h = relu(W1 z + b1) ; pix = sigmoid(W2 h + b2) ----
    if (tid < 32) {
        float acc = b1[tid];
        #pragma unroll
        for (int k = 0; k < 12; ++k) acc += W1[tid*12 + k] * sz[k];
        sh[tid] = acc > 0.f ? acc : 0.f;
    }
    __syncthreads();
    if (tid < 16) {
        float acc = b2[tid];
        #pragma unroll
        for (int k = 0; k < 32; ++k) acc += W2[tid*32 + k] * sh[k];
        pix[tid] = 1.f / (1.f + expf(-acc));
    }
}

// ---------------------------------------------------------------------------
// Kernel B: broadcast the 16 floats to (B,1,4,4) = 16M floats, float4 stores.
// ---------------------------------------------------------------------------
__global__ __launch_bounds__(256) void bcast_kernel(
    const float4* __restrict__ pix4, float4* __restrict__ out4)
{
    const int i = blockIdx.x * 256 + threadIdx.x;
    out4[i] = pix4[i & 3];
}

extern "C" void kernel_launch(void* const* d_in, const int* in_sizes, int n_in,
                              void* d_out, int out_size, void* d_ws, size_t ws_size,
                              hipStream_t stream) {
    // inputs: 0=images (ignored), 1=qweights, 2=W1, 3=b1, 4=W2, 5=b2
    const float* qw = (const float*)d_in[1];
    const float* W1 = (const float*)d_in[2];
    const float* b1 = (const float*)d_in[3];
    const float* W2 = (const float*)d_in[4];
    const float* b2 = (const float*)d_in[5];
    float* pix = (float*)d_ws;   // 16 floats of scratch

    circuit_kernel<<<1, 1024, 0, stream>>>(qw, W1, b1, W2, b2, pix);

    const int n4 = out_size / 4;               // 4,194,304 float4
    bcast_kernel<<<n4 / 256, 256, 0, stream>>>((const float4*)pix,
                                               (float4*)d_out);
}

// Round 2
// 133.442 us; speedup vs baseline: 1.2722x; 1.2722x over previous
//
#include <hip/hip_runtime.h>
#include <math.h>

#define NQ  12
#define NST 4096   // 2^12 amplitudes

// LDS address swizzle: spreads low-bit quartet passes across banks.
// Self-inverse, bijective on [0,4096) (only modifies bits 0-3).
__device__ __forceinline__ int P(int i) { return i ^ ((i >> 4) & 0xF); }

// Apply complex 2x2 gate (rows u0,u1 as (r0,i0,r1,i1)) to amplitude pair.
__device__ __forceinline__ void apply2(const float4& u0, const float4& u1,
                                       float2& v0, float2& v1) {
    const float n0r = u0.x*v0.x - u0.y*v0.y + u0.z*v1.x - u0.w*v1.y;
    const float n0i = u0.x*v0.y + u0.y*v0.x + u0.z*v1.y + u0.w*v1.x;
    const float n1r = u1.x*v0.x - u1.y*v0.y + u1.z*v1.x - u1.w*v1.y;
    const float n1i = u1.x*v0.y + u1.y*v0.x + u1.z*v1.y + u1.w*v1.x;
    v0 = make_float2(n0r, n0i);
    v1 = make_float2(n1r, n1i);
}

// ---------------------------------------------------------------------------
// Kernel A: statevector sim, one block. Qubit q <-> bit (11-q) of flat index.
// Structure per layer: 6 fused 2-qubit gate passes + 1 permutation pass
// (the 12-CNOT ring is a GF(2)-linear basis relabeling: prefix-XOR).
// ---------------------------------------------------------------------------
__global__ __launch_bounds__(1024) void circuit_kernel(
    const float* __restrict__ qw,   // (3,12,3)
    const float* __restrict__ W1,   // (32,12)
    const float* __restrict__ b1,   // (32,)
    const float* __restrict__ W2,   // (16,32)
    const float* __restrict__ b2,   // (16,)
    float* __restrict__ pix)        // 16 outputs -> d_ws
{
    __shared__ float2 amp[NST];     // logical index i stored at amp[P(i)]
    __shared__ float2 cs[108];      // (cos(a/2), sin(a/2)) per angle
    __shared__ float4 gmat[36][2];  // U = RZ*RY*RX rows per gate
    __shared__ float  szv[NQ];
    __shared__ float  sh[32];

    const int tid = threadIdx.x;

    // init |0...0>
    for (int i = tid; i < NST; i += 1024) amp[i] = make_float2(0.f, 0.f);
    if (tid == 0) amp[0] = make_float2(1.f, 0.f);   // P(0)==0
    // phase 0a: one sincos per angle, in parallel
    if (tid < 108) {
        const float a = 0.5f * qw[tid];
        cs[tid] = make_float2(cosf(a), sinf(a));
    }
    __syncthreads();
    // phase 0b: build the 36 single-qubit matrices U = RZ @ RY @ RX
    if (tid < 36) {
        const float cx = cs[3*tid+0].x, sx = cs[3*tid+0].y;
        const float cy = cs[3*tid+1].x, sy = cs[3*tid+1].y;
        const float cz = cs[3*tid+2].x, sz = cs[3*tid+2].y;
        const float a00r =  cy*cx, a00i =  sy*sx;   // A = RY @ RX
        const float a01r = -sy*cx, a01i = -cy*sx;
        const float a10r =  sy*cx, a10i = -cy*sx;
        const float a11r =  cy*cx, a11i = -sy*sx;
        // row0 *= e^{-i tz/2}, row1 *= e^{+i tz/2}
        gmat[tid][0] = make_float4(cz*a00r + sz*a00i, cz*a00i - sz*a00r,
                                   cz*a01r + sz*a01i, cz*a01i - sz*a01r);
        gmat[tid][1] = make_float4(cz*a10r - sz*a10i, cz*a10i + sz*a10r,
                                   cz*a11r - sz*a11i, cz*a11i + sz*a11r);
    }
    __syncthreads();

    for (int l = 0; l < 3; ++l) {
        // ---- 6 passes, each applying gates on qubits (2j, 2j+1) ----
        for (int j = 0; j < 6; ++j) {
            const int g = l*12 + 2*j;
            const float4 ua0 = gmat[g][0],   ua1 = gmat[g][1];    // qubit 2j
            const float4 ub0 = gmat[g+1][0], ub1 = gmat[g+1][1];  // qubit 2j+1
            const int pb = 10 - 2*j;            // bit pos of qubit 2j+1
            const int bb = 1 << pb, ba = bb << 1;
            const int base = ((tid >> pb) << (pb + 2)) | (tid & (bb - 1));
            const int i00 = P(base),      i01 = P(base | bb);
            const int i10 = P(base | ba), i11 = P(base | ba | bb);
            float2 v00 = amp[i00], v01 = amp[i01];
            float2 v10 = amp[i10], v11 = amp[i11];
            apply2(ua0, ua1, v00, v10);   // qubit 2j   (bit ba)
            apply2(ua0, ua1, v01, v11);
            apply2(ub0, ub1, v00, v01);   // qubit 2j+1 (bit bb)
            apply2(ub0, ub1, v10, v11);
            amp[i00] = v00; amp[i01] = v01; amp[i10] = v10; amp[i11] = v11;
            __syncthreads();
        }
        // ---- CNOT ring as one permutation: y_q = x_0^..^x_q (q>=1),
        //      y_0 = x_1^..^x_11. Bit-parallel via suffix-XOR over flat bits.
        {
            int dst[4]; float2 val[4];
            #pragma unroll
            for (int k = 0; k < 4; ++k) {
                const int f = tid + 1024*k;
                val[k] = amp[P(f)];
                int t = f;
                t ^= t >> 1; t ^= t >> 2; t ^= t >> 4; t ^= t >> 8;
                const int gd = (t & 0x7FF) | (((t ^ (f >> 11)) & 1) << 11);
                dst[k] = P(gd);
            }
            __syncthreads();   // all reads complete before scatter writes
            #pragma unroll
            for (int k = 0; k < 4; ++k) amp[dst[k]] = val[k];
            __syncthreads();
        }
    }

    // ---- <Z_q>: wave w reduces qubit w ----
    const int lane = tid & 63;
    const int w    = tid >> 6;
    if (w < NQ) {
        const int bit = 1 << (11 - w);
        float s = 0.f;
        for (int i = lane; i < NST; i += 64) {
            const float2 a = amp[P(i)];
            const float pr = a.x*a.x + a.y*a.y;
            s += (i & bit) ? -pr : pr;
        }
        #pragma unroll
        for (int off = 32; off > 0; off >>= 1) s += __shfl_down(s, off, 64);
        if (lane == 0) szv[w] = s;
    }
    __syncthreads();

    // ---- MLP: h = relu(W1 z + b1); pix = sigmoid(W2 h + b2) ----
    if (tid < 32) {
        float acc = b1[tid];
        #pragma unroll
        for (int k = 0; k < 12; ++k) acc += W1[tid*12 + k] * szv[k];
        sh[tid] = acc > 0.f ? acc : 0.f;
    }
    __syncthreads();
    if (tid < 16) {
        float acc = b2[tid];
        #pragma unroll
        for (int k = 0; k < 32; ++k) acc += W2[tid*32 + k] * sh[k];
        pix[tid] = 1.f / (1.f + expf(-acc));
    }
}

// ---------------------------------------------------------------------------
// Kernel B: broadcast 16 floats to (B,1,4,4) = 64 MiB, float4 stores.
// ---------------------------------------------------------------------------
__global__ __launch_bounds__(256) void bcast_kernel(
    const float4* __restrict__ pix4, float4* __restrict__ out4)
{
    const int i = blockIdx.x * 256 + threadIdx.x;
    out4[i] = pix4[i & 3];
}

extern "C" void kernel_launch(void* const* d_in, const int* in_sizes, int n_in,
                              void* d_out, int out_size, void* d_ws, size_t ws_size,
                              hipStream_t stream) {
    // inputs: 0=images (ignored), 1=qweights, 2=W1, 3=b1, 4=W2, 5=b2
    const float* qw = (const float*)d_in[1];
    const float* W1 = (const float*)d_in[2];
    const float* b1 = (const float*)d_in[3];
    const float* W2 = (const float*)d_in[4];
    const float* b2 = (const float*)d_in[5];
    float* pix = (float*)d_ws;   // 16 floats of scratch

    circuit_kernel<<<1, 1024, 0, stream>>>(qw, W1, b1, W2, b2, pix);

    const int n4 = out_size / 4;               // 4,194,304 float4
    bcast_kernel<<<n4 / 256, 256, 0, stream>>>((const float4*)pix,
                                               (float4*)d_out);
}

// Round 4
// 123.274 us; speedup vs baseline: 1.3772x; 1.0825x over previous
//
#include <hip/hip_runtime.h>
#include <math.h>

#define NTH 512   // 8 waves; each thread owns an octet (8 amps = 3 qubits/pass)

// Storage swizzle: logical amp i lives at amp[Sw(i)]. XOR bits 0-2 with bits
// 6-8: makes every pass's octet pattern hit the b64-minimal bank distribution.
__device__ __forceinline__ int Sw(int i) { return i ^ ((i >> 6) & 7); }

// CNOT-ring basis map (GF(2)-linear): state_after[Fr(i)] = state_before[i].
// Flat bit b holds qubit (11-b); ring CNOT(q,q+1 mod 12) => suffix-XOR in
// flat-bit space + parity fix on bit 11. (Verified correct in R2 kernel.)
__device__ __forceinline__ int Fr(int i) {
    int x = i; x ^= x >> 1; x ^= x >> 2; x ^= x >> 4; x ^= x >> 8;
    return (x & 0x7FF) | (((x ^ (i >> 11)) & 1) << 11);
}

__device__ __forceinline__ float2 cmul(float2 a, float2 b) {
    return make_float2(a.x*b.x - a.y*b.y, a.x*b.y + a.y*b.x);
}

// Complex 2x2 gate, rows u0,u1 = (u_r0, u_i0, u_r1, u_i1); v0 = bit-clear amp.
__device__ __forceinline__ void apply2(const float4 u0, const float4 u1,
                                       float2& v0, float2& v1) {
    const float n0r = u0.x*v0.x - u0.y*v0.y + u0.z*v1.x - u0.w*v1.y;
    const float n0i = u0.x*v0.y + u0.y*v0.x + u0.z*v1.y + u0.w*v1.x;
    const float n1r = u1.x*v0.x - u1.y*v0.y + u1.z*v1.x - u1.w*v1.y;
    const float n1i = u1.x*v0.y + u1.y*v0.x + u1.z*v1.y + u1.w*v1.x;
    v0 = make_float2(n0r, n0i);
    v1 = make_float2(n1r, n1i);
}

// One LDS pass: 3 gates on flat bits PLOW+2, PLOW+1, PLOW (qubits 9-PLOW..11-PLOW).
// MODE 0: write back in place. MODE 1: ring-fold scatter write (barrier first:
// dst set != src set across threads). MODE 2: no write — accumulate the 12
// signed probability partials using the ring-folded logical index.
template<int PLOW, int MODE>
__device__ __forceinline__ void do_pass(float2* amp, const float4 (*gmat)[2],
                                        int gbase, int t, float* zacc) {
    int base;
    if      (PLOW == 9) base = t;
    else if (PLOW == 6) base = ((t >> 6) << 9) | (t & 63);
    else if (PLOW == 3) base = ((t >> 3) << 6) | (t & 7);
    else                base = t << 3;

    float2 v[8]; int idx[8];
    #pragma unroll
    for (int r = 0; r < 8; ++r) {
        idx[r] = Sw(base | (r << PLOW));
        v[r] = amp[idx[r]];
    }
    #pragma unroll
    for (int k = 2; k >= 0; --k) {
        const int q = 11 - (PLOW + k);          // qubit of flat bit PLOW+k
        const float4 u0 = gmat[gbase + q][0];
        const float4 u1 = gmat[gbase + q][1];
        const int m = 1 << k;
        #pragma unroll
        for (int r = 0; r < 8; ++r)
            if (!(r & m)) apply2(u0, u1, v[r], v[r | m]);
    }
    if (MODE == 0) {
        #pragma unroll
        for (int r = 0; r < 8; ++r) amp[idx[r]] = v[r];
    } else if (MODE == 1) {
        __syncthreads();   // all reads done before cross-thread scatter
        #pragma unroll
        for (int r = 0; r < 8; ++r) amp[Sw(Fr(base | (r << PLOW)))] = v[r];
    } else {
        #pragma unroll
        for (int r = 0; r < 8; ++r) {
            const int x = Fr(base | (r << PLOW));   // final logical index
            const float p = v[r].x*v[r].x + v[r].y*v[r].y;
            #pragma unroll
            for (int q = 0; q < 12; ++q)
                zacc[q] += ((x >> (11 - q)) & 1) ? -p : p;
        }
    }
}

__global__ __launch_bounds__(NTH) void circuit_kernel(
    const float* __restrict__ qw,   // (3,12,3)
    const float* __restrict__ W1,   // (32,12)
    const float* __restrict__ b1,   // (32,)
    const float* __restrict__ W2,   // (16,32)
    const float* __restrict__ b2,   // (16,)
    float* __restrict__ pix)        // 16 outputs -> d_ws
{
    __shared__ float2 amp[4096];     // 32 KiB, swizzled storage
    __shared__ float4 gmat[36][2];   // U = RZ*RY*RX rows per gate
    __shared__ float  zp2[96];       // per-wave qubit partials (8 waves x 12)
    __shared__ float  szv[12];
    __shared__ float  sh[32];

    const int tid = threadIdx.x;

    // ---- build the 36 gate matrices (one thread per gate) ----
    if (tid < 36) {
        float sx, cx, sy, cy, sz, cz;
        sincosf(0.5f * qw[tid*3+0], &sx, &cx);
        sincosf(0.5f * qw[tid*3+1], &sy, &cy);
        sincosf(0.5f * qw[tid*3+2], &sz, &cz);
        const float a00r =  cy*cx, a00i =  sy*sx;    // A = RY @ RX
        const float a01r = -sy*cx, a01i = -cy*sx;
        const float a10r =  sy*cx, a10i = -cy*sx;
        const float a11r =  cy*cx, a11i = -sy*sx;
        // row0 *= e^{-i tz/2}, row1 *= e^{+i tz/2}
        gmat[tid][0] = make_float4(cz*a00r + sz*a00i, cz*a00i - sz*a00r,
                                   cz*a01r + sz*a01i, cz*a01i - sz*a01r);
        gmat[tid][1] = make_float4(cz*a10r - sz*a10i, cz*a10i + sz*a10r,
                                   cz*a11r - sz*a11i, cz*a11i + sz*a11r);
    }
    __syncthreads();

    // ---- pass 0: layer 1 is a product state from |0..0>; build directly,
    //      with layer-1 ring permute folded into the write addressing ----
    {
        float2 pp = make_float2(1.f, 0.f);
        #pragma unroll
        for (int b = 11; b >= 3; --b) {            // i bit b = t bit (b-3)
            const int q = 11 - b;
            const float4 g = gmat[q][(tid >> (b - 3)) & 1];
            pp = cmul(pp, make_float2(g.x, g.y));  // column 0 of row sel
        }
        float2 c9[2], c10[2], c11[2];
        #pragma unroll
        for (int s = 0; s < 2; ++s) {
            c9[s]  = make_float2(gmat[9][s].x,  gmat[9][s].y);
            c10[s] = make_float2(gmat[10][s].x, gmat[10][s].y);
            c11[s] = make_float2(gmat[11][s].x, gmat[11][s].y);
        }
        #pragma unroll
        for (int r = 0; r < 8; ++r) {
            const float2 v = cmul(pp,
                cmul(c9[(r>>2)&1], cmul(c10[(r>>1)&1], c11[r&1])));
            amp[Sw(Fr((tid << 3) | r))] = v;
        }
    }
    __syncthreads();

    float zacc[12];
    #pragma unroll
    for (int q = 0; q < 12; ++q) zacc[q] = 0.f;

    // ---- layer 2 (gates 12..23): 4 passes, ring folded into the last ----
    do_pass<9,0>(amp, gmat, 12, tid, zacc); __syncthreads();
    do_pass<6,0>(amp, gmat, 12, tid, zacc); __syncthreads();
    do_pass<3,0>(amp, gmat, 12, tid, zacc); __syncthreads();
    do_pass<0,1>(amp, gmat, 12, tid, zacc); __syncthreads();
    // ---- layer 3 (gates 24..35): last pass emits partials, no writeback ----
    do_pass<9,0>(amp, gmat, 24, tid, zacc); __syncthreads();
    do_pass<6,0>(amp, gmat, 24, tid, zacc); __syncthreads();
    do_pass<3,0>(amp, gmat, 24, tid, zacc); __syncthreads();
    do_pass<0,2>(amp, gmat, 24, tid, zacc);

    // ---- in-wave reduction: split qubit set across lanes, then butterfly ----
    const int lane = tid & 63;
    float z6[6];
    #pragma unroll
    for (int k = 0; k < 6; ++k) {
        const float send = (lane & 1) ? zacc[k]     : zacc[k+6];
        const float keep = (lane & 1) ? zacc[k+6]   : zacc[k];
        z6[k] = keep + __shfl_xor(send, 1);
    }
    float z3[3];
    #pragma unroll
    for (int k = 0; k < 3; ++k) {
        const float send = (lane & 2) ? z6[k]   : z6[k+3];
        const float keep = (lane & 2) ? z6[k+3] : z6[k];
        z3[k] = keep + __shfl_xor(send, 2);
    }
    #pragma unroll
    for (int m = 4; m <= 32; m <<= 1) {
        #pragma unroll
        for (int k = 0; k < 3; ++k) z3[k] += __shfl_xor(z3[k], m);
    }
    // lane holds qubits qb..qb+2, qb = 6*(lane&1) + 3*((lane>>1)&1)
    if (lane < 4) {
        const int qb = 6*(lane & 1) + 3*((lane >> 1) & 1);
        const int w  = tid >> 6;
        #pragma unroll
        for (int k = 0; k < 3; ++k) zp2[w*12 + qb + k] = z3[k];
    }
    __syncthreads();
    if (tid < 12) {
        float s = 0.f;
        #pragma unroll
        for (int w = 0; w < 8; ++w) s += zp2[w*12 + tid];
        szv[tid] = s;
    }
    __syncthreads();

    // ---- MLP: h = relu(W1 z + b1); pix = sigmoid(W2 h + b2) ----
    if (tid < 32) {
        float acc = b1[tid];
        #pragma unroll
        for (int k = 0; k < 12; ++k) acc += W1[tid*12 + k] * szv[k];
        sh[tid] = acc > 0.f ? acc : 0.f;
    }
    __syncthreads();
    if (tid < 16) {
        float acc = b2[tid];
        #pragma unroll
        for (int k = 0; k < 32; ++k) acc += W2[tid*32 + k] * sh[k];
        pix[tid] = 1.f / (1.f + expf(-acc));
    }
}

// ---------------------------------------------------------------------------
// Kernel B: broadcast 16 floats to (B,1,4,4) = 64 MiB, float4 stores.
// ---------------------------------------------------------------------------
__global__ __launch_bounds__(256) void bcast_kernel(
    const float4* __restrict__ pix4, float4* __restrict__ out4)
{
    const int i = blockIdx.x * 256 + threadIdx.x;
    out4[i] = pix4[i & 3];
}

extern "C" void kernel_launch(void* const* d_in, const int* in_sizes, int n_in,
                              void* d_out, int out_size, void* d_ws, size_t ws_size,
                              hipStream_t stream) {
    // inputs: 0=images (ignored), 1=qweights, 2=W1, 3=b1, 4=W2, 5=b2
    const float* qw = (const float*)d_in[1];
    const float* W1 = (const float*)d_in[2];
    const float* b1 = (const float*)d_in[3];
    const float* W2 = (const float*)d_in[4];
    const float* b2 = (const float*)d_in[5];
    float* pix = (float*)d_ws;   // 16 floats of scratch

    circuit_kernel<<<1, NTH, 0, stream>>>(qw, W1, b1, W2, b2, pix);

    const int n4 = out_size / 4;               // 4,194,304 float4
    bcast_kernel<<<n4 / 256, 256, 0, stream>>>((const float4*)pix,
                                               (float4*)d_out);
}